// Round 1
// baseline (224.222 us; speedup 1.0000x reference)
//
#include <hip/hip_runtime.h>

#define WIN 7
#define TH 32                 // output tile rows
#define TW 32                 // output tile cols
#define IH (TH + WIN - 1)     // 38 input rows per tile
#define IW (TW + WIN - 1)     // 38 input cols per tile
#define XSTR 39               // LDS stride for staged inputs
#define VSTR 41               // LDS stride for vertical sums (2-way max bank aliasing in phase 3)
#define H 256
#define W 256
#define OH 250
#define OW 250
#define NIMG 256              // B*D = 4*64
#define TILES_X 8
#define TILES_Y 8
#define NBLK (TILES_X * TILES_Y * NIMG)   // 16384 partial sums

__global__ __launch_bounds__(256) void ssim_tile_kernel(
    const float* __restrict__ X, const float* __restrict__ Y,
    float* __restrict__ partial)
{
    __shared__ float xs[IH][XSTR];
    __shared__ float ys[IH][XSTR];
    __shared__ float vs[5][TH][VSTR];
    __shared__ float wsum[4];

    const int tid = threadIdx.x;
    const int tx = blockIdx.x, ty = blockIdx.y, img = blockIdx.z;
    const int r0 = ty * TH, c0 = tx * TW;
    const float* Xi = X + (size_t)img * (H * W);
    const float* Yi = Y + (size_t)img * (H * W);

    // ---- Phase 1: stage input halo tile (clamped at image edge; outputs
    // beyond the valid range are filtered in phase 3) ----
    for (int e = tid; e < IH * IW; e += 256) {
        int r = e / IW, c = e - r * IW;
        int gr = min(r0 + r, H - 1);
        int gc = min(c0 + c, W - 1);
        xs[r][c] = Xi[gr * W + gc];
        ys[r][c] = Yi[gr * W + gc];
    }
    __syncthreads();

    // ---- Phase 2: vertical 7-tap sums of the 5 moments ----
    for (int e = tid; e < TH * IW; e += 256) {
        int r = e / IW, c = e - r * IW;
        float sx = 0.f, sy = 0.f, sxx = 0.f, syy = 0.f, sxy = 0.f;
        #pragma unroll
        for (int k = 0; k < WIN; ++k) {
            float xv = xs[r + k][c];
            float yv = ys[r + k][c];
            sx += xv;
            sy += yv;
            sxx = fmaf(xv, xv, sxx);
            syy = fmaf(yv, yv, syy);
            sxy = fmaf(xv, yv, sxy);
        }
        vs[0][r][c] = sx;
        vs[1][r][c] = sy;
        vs[2][r][c] = sxx;
        vs[3][r][c] = syy;
        vs[4][r][c] = sxy;
    }
    __syncthreads();

    // ---- Phase 3: horizontal sliding 7-window + SSIM + local accumulate ----
    const int row = tid >> 3;          // 0..31
    const int cg  = (tid & 7) * 4;     // col start: 0,4,...,28

    float sums[5];
    float lead[5][3];                  // first 3 columns (the ones that leave)
    #pragma unroll
    for (int m = 0; m < 5; ++m) {
        float acc = 0.f;
        #pragma unroll
        for (int j = 0; j < WIN; ++j) {
            float v = vs[m][row][cg + j];
            if (j < 3) lead[m][j] = v;
            acc += v;
        }
        sums[m] = acc;
    }

    const float inv_np   = 1.0f / 49.0f;
    const float cov_norm = 49.0f / 48.0f;
    const float C1 = 0.0001f;   // (0.01*1)^2
    const float C2 = 0.0009f;   // (0.03*1)^2

    float lsum = 0.f;
    const int orow = r0 + row;
    #pragma unroll
    for (int s = 0; s < 4; ++s) {
        const int ocol = c0 + cg + s;
        float ux  = sums[0] * inv_np;
        float uy  = sums[1] * inv_np;
        float uxx = sums[2] * inv_np;
        float uyy = sums[3] * inv_np;
        float uxy = sums[4] * inv_np;
        float vx  = cov_norm * (uxx - ux * ux);
        float vy  = cov_norm * (uyy - uy * uy);
        float vxy = cov_norm * (uxy - ux * uy);
        float A1 = 2.f * ux * uy + C1;
        float A2 = 2.f * vxy + C2;
        float B1 = ux * ux + uy * uy + C1;
        float B2 = vx + vy + C2;
        float S = (A1 * A2) * __builtin_amdgcn_rcpf(B1 * B2);
        if (orow < OH && ocol < OW) lsum += S;
        if (s < 3) {
            #pragma unroll
            for (int m = 0; m < 5; ++m)
                sums[m] += vs[m][row][cg + WIN + s] - lead[m][s];
        }
    }

    // ---- Block reduction: wave shuffle + LDS, one float per block ----
    #pragma unroll
    for (int off = 32; off > 0; off >>= 1)
        lsum += __shfl_down(lsum, off, 64);
    if ((tid & 63) == 0) wsum[tid >> 6] = lsum;
    __syncthreads();
    if (tid == 0) {
        float t = wsum[0] + wsum[1] + wsum[2] + wsum[3];
        partial[(blockIdx.z * TILES_Y + blockIdx.y) * TILES_X + blockIdx.x] = t;
    }
}

__global__ __launch_bounds__(256) void ssim_reduce_kernel(
    const float* __restrict__ partial, float* __restrict__ out)
{
    const int tid = threadIdx.x;
    double acc = 0.0;
    for (int i = tid; i < NBLK; i += 256)
        acc += (double)partial[i];
    #pragma unroll
    for (int off = 32; off > 0; off >>= 1)
        acc += __shfl_down(acc, off, 64);
    __shared__ double wsumd[4];
    if ((tid & 63) == 0) wsumd[tid >> 6] = acc;
    __syncthreads();
    if (tid == 0) {
        double total = wsumd[0] + wsumd[1] + wsumd[2] + wsumd[3];
        float loss = (float)(1.0 - total / 16000000.0);
        out[0] = loss;
        out[1] = loss;
        out[2] = loss;
        out[3] = loss;
    }
}

extern "C" void kernel_launch(void* const* d_in, const int* in_sizes, int n_in,
                              void* d_out, int out_size, void* d_ws, size_t ws_size,
                              hipStream_t stream) {
    const float* X = (const float*)d_in[0];
    const float* Y = (const float*)d_in[1];
    // d_in[2] is the 7x7 uniform filter (all 1/49) — constant-folded into the kernel.
    float* out = (float*)d_out;
    float* partial = (float*)d_ws;   // 16384 floats = 64 KB

    dim3 grid(TILES_X, TILES_Y, NIMG);
    hipLaunchKernelGGL(ssim_tile_kernel, grid, dim3(256), 0, stream, X, Y, partial);
    hipLaunchKernelGGL(ssim_reduce_kernel, dim3(1), dim3(256), 0, stream, partial, out);
}

// Round 2
// 160.044 us; speedup vs baseline: 1.4010x; 1.4010x over previous
//
#include <hip/hip_runtime.h>

#define H 256
#define W 256
#define W4 (W / 4)            // 64 float4 per image row
#define OWID 250
#define OHEI 250
#define NIMG 256              // B*D
#define BAND 28               // output rows per wave (multiple of 7 for unroll)
#define NBANDS 9              // ceil(250/28): 8 full bands + one 26-row band
#define NBLK (NBANDS * NIMG)  // 2304 partials
#define VPAD 264              // per-moment LDS floats (256 + 8 window tail)

__device__ __forceinline__ float4 f4zero() { return make_float4(0.f, 0.f, 0.f, 0.f); }

// s += n - o  (component-wise)
__device__ __forceinline__ void vacc(float4& s, const float4 n, const float4 o) {
    s.x += n.x - o.x; s.y += n.y - o.y; s.z += n.z - o.z; s.w += n.w - o.w;
}
// s += a*b - c*d  (component-wise)
__device__ __forceinline__ void vaccp(float4& s, const float4 a, const float4 b,
                                      const float4 c, const float4 d) {
    s.x += a.x * b.x - c.x * d.x;
    s.y += a.y * b.y - c.y * d.y;
    s.z += a.z * b.z - c.z * d.z;
    s.w += a.w * b.w - c.w * d.w;
}

__global__ __launch_bounds__(64) void ssim_band_kernel(
    const float* __restrict__ X, const float* __restrict__ Y,
    float* __restrict__ partial)
{
    // 5 vertical-moment rows staged in LDS for the horizontal 7-tap.
    // b128 access pattern (lane -> banks 4t..4t+3 mod 32) is bank-uniform.
    __shared__ float vsx[VPAD], vsy[VPAD], vsxx[VPAD], vsyy[VPAD], vsxy[VPAD];

    const int lane = threadIdx.x;   // 0..63, owns cols 4*lane..4*lane+3
    const int band = blockIdx.x;    // 0..8
    const int img  = blockIdx.y;    // 0..255
    const int r0 = band * BAND;
    const int out_rows = (OHEI - r0 < BAND) ? (OHEI - r0) : BAND;
    const int rows_in = out_rows + 6;    // input rows this band (<= 34, all <= 255)

    const float4* Xp = (const float4*)X + ((size_t)img * H + r0) * W4 + lane;
    const float4* Yp = (const float4*)Y + ((size_t)img * H + r0) * W4 + lane;

    // 7-deep circular history of raw x,y (registers; all indices static).
    float4 xh[7], yh[7];
    float4 sx = f4zero(), sy = f4zero(), sxx = f4zero(), syy = f4zero(), sxy = f4zero();

    // Prologue: rows 0..5 fill history + sums. Slot 6 = zeros so the first
    // main iteration (row 6) subtracts nothing.
    #pragma unroll
    for (int i = 0; i < 6; ++i) {
        float4 xv = Xp[i * W4];
        float4 yv = Yp[i * W4];
        xh[i] = xv; yh[i] = yv;
        vacc(sx, xv, f4zero());
        vacc(sy, yv, f4zero());
        vaccp(sxx, xv, xv, f4zero(), f4zero());
        vaccp(syy, yv, yv, f4zero(), f4zero());
        vaccp(sxy, xv, yv, f4zero(), f4zero());
    }
    xh[6] = f4zero(); yh[6] = f4zero();

    // Pre-load row 6.
    float4 xn = Xp[6 * W4];
    float4 yn = Yp[6 * W4];

    const float inv_np   = 1.0f / 49.0f;
    const float cov_norm = 49.0f / 48.0f;
    const float C1 = 1e-4f;    // (0.01)^2
    const float C2 = 9e-4f;    // (0.03)^2
    float lsum = 0.0f;

    // Outer step of 7 keeps base % 7 == 6 constant -> history index (6+i)%7
    // is a compile-time constant in the unrolled inner loop (no reg shifts).
    for (int base = 6; base < rows_in; base += 7) {
        #pragma unroll
        for (int i = 0; i < 7; ++i) {
            const int r = base + i;
            if (r < rows_in) {                 // wave-uniform guard
                const int slot = (6 + i) % 7;  // static
                // Prefetch next row early; consumed next iteration.
                float4 xf, yf;
                const bool more = (r + 1 < rows_in);
                if (more) { xf = Xp[(r + 1) * W4]; yf = Yp[(r + 1) * W4]; }

                // Vertical slide: add entering row, subtract leaving row.
                const float4 xo = xh[slot], yo = yh[slot];
                vacc(sx, xn, xo);
                vacc(sy, yn, yo);
                vaccp(sxx, xn, xn, xo, xo);
                vaccp(syy, yn, yn, yo, yo);
                vaccp(sxy, xn, yn, xo, yo);
                xh[slot] = xn; yh[slot] = yn;

                // Stage this output row's 5 vertical-sum vectors.
                ((float4*)vsx)[lane] = sx;
                ((float4*)vsy)[lane] = sy;
                ((float4*)vsxx)[lane] = sxx;
                ((float4*)vsyy)[lane] = syy;
                ((float4*)vsxy)[lane] = sxy;
                __syncthreads();   // 1-wave block: waitcnt + cheap barrier

                // Horizontal 7-tap sliding window. Own 4 sums are already in
                // registers; only neighbor floats +4..+9 come from LDS.
                float wx[4], wy[4], wxx[4], wyy[4], wxy[4];
                #define HWIN(VS, S, WA)                                        \
                {                                                              \
                    float4 b = ((const float4*)VS)[lane + 1];                  \
                    float2 c = *(const float2*)&VS[4 * lane + 8];              \
                    WA[0] = S.x + S.y + S.z + S.w + b.x + b.y + b.z;           \
                    WA[1] = WA[0] - S.x + b.w;                                 \
                    WA[2] = WA[1] - S.y + c.x;                                 \
                    WA[3] = WA[2] - S.z + c.y;                                 \
                }
                HWIN(vsx,  sx,  wx)
                HWIN(vsy,  sy,  wy)
                HWIN(vsxx, sxx, wxx)
                HWIN(vsyy, syy, wyy)
                HWIN(vsxy, sxy, wxy)
                #undef HWIN
                __syncthreads();   // protect reads from next iteration's writes

                // SSIM for this lane's 4 output columns.
                #pragma unroll
                for (int s = 0; s < 4; ++s) {
                    float ux  = wx[s]  * inv_np;
                    float uy  = wy[s]  * inv_np;
                    float uxx = wxx[s] * inv_np;
                    float uyy = wyy[s] * inv_np;
                    float uxy = wxy[s] * inv_np;
                    float vx  = cov_norm * (uxx - ux * ux);
                    float vy  = cov_norm * (uyy - uy * uy);
                    float vxy = cov_norm * (uxy - ux * uy);
                    float A1 = 2.f * ux * uy + C1;
                    float A2 = 2.f * vxy + C2;
                    float B1 = ux * ux + uy * uy + C1;
                    float B2 = vx + vy + C2;
                    float S = (A1 * A2) * __builtin_amdgcn_rcpf(B1 * B2);
                    if (4 * lane + s < OWID) lsum += S;   // mask cols >= 250
                }
                xn = xf; yn = yf;
            }
        }
    }

    // Wave reduction -> one partial per block.
    #pragma unroll
    for (int off = 32; off > 0; off >>= 1)
        lsum += __shfl_down(lsum, off, 64);
    if (lane == 0) partial[img * NBANDS + band] = lsum;
}

__global__ __launch_bounds__(256) void ssim_reduce_kernel(
    const float* __restrict__ partial, float* __restrict__ out)
{
    const int tid = threadIdx.x;
    double acc = 0.0;
    for (int i = tid; i < NBLK; i += 256)
        acc += (double)partial[i];
    #pragma unroll
    for (int off = 32; off > 0; off >>= 1)
        acc += __shfl_down(acc, off, 64);
    __shared__ double wsumd[4];
    if ((tid & 63) == 0) wsumd[tid >> 6] = acc;
    __syncthreads();
    if (tid == 0) {
        double total = wsumd[0] + wsumd[1] + wsumd[2] + wsumd[3];
        float loss = (float)(1.0 - total / 16000000.0);
        out[0] = loss; out[1] = loss; out[2] = loss; out[3] = loss;
    }
}

extern "C" void kernel_launch(void* const* d_in, const int* in_sizes, int n_in,
                              void* d_out, int out_size, void* d_ws, size_t ws_size,
                              hipStream_t stream) {
    const float* X = (const float*)d_in[0];
    const float* Y = (const float*)d_in[1];
    // d_in[2] is the uniform 7x7 filter (1/49 everywhere) — constant-folded.
    float* out = (float*)d_out;
    float* partial = (float*)d_ws;   // 2304 floats = 9.2 KB

    hipLaunchKernelGGL(ssim_band_kernel, dim3(NBANDS, NIMG), dim3(64), 0, stream,
                       X, Y, partial);
    hipLaunchKernelGGL(ssim_reduce_kernel, dim3(1), dim3(256), 0, stream,
                       partial, out);
}